// Round 8
// baseline (533.827 us; speedup 1.0000x reference)
//
#include <hip/hip_runtime.h>
#include <hip/hip_bf16.h>

// B=8, T=4096, C=384, H=64 causal single-head attention. fp32 in/out.
//
// Round-8: attention makespan = critical path of the longest (qt=63) block.
// 4-way split-K inside a 1024-thr block (16 waves = 4 groups x 4 waves,
// group g takes tiles t = 4j+g): longest chain 32 -> 16 iterations, and
// 2 blocks/CU x 16 waves = 32 waves/CU (8/SIMD) at VGPR<=64. Barrier-free
// k-loop (fragment-layout K/V direct from global, round 7). 3-round
// sequential online-softmax merge through one LDS buffer at the end.
//
//  k_frag layout: [rt=row/16][c8=col/8][i=row%16][j=col%8]   (bf16)
//  vt_frag layout: [st=row/64][dt=d/16][sc=s%64/8][i=d%16][j=s%8]

typedef __bf16 bf16x8 __attribute__((ext_vector_type(8)));
typedef float  f32x4  __attribute__((ext_vector_type(4)));

#define BB   8
#define TT   4096
#define CC   384
#define HH   64
#define NROW (BB*TT)       // 32768
// C^-0.5 * log2(e): fold softmax scale + exp2 conversion into q at projection
#define QSCALE (0.05103103630798288f * 1.4426950408889634f)

#if __has_builtin(__builtin_amdgcn_exp2f)
#define EXP2(x) __builtin_amdgcn_exp2f(x)
#else
#define EXP2(x) exp2f(x)
#endif

// Compiler memory fence + HW LDS drain: orders wave-local LDS write->read.
#define LDS_ROUNDTRIP_FENCE() __asm volatile("s_waitcnt lgkmcnt(0)" ::: "memory")

__device__ __forceinline__ unsigned short f2bf(float f) {
    __bf16 h = (__bf16)f;
    return __builtin_bit_cast(unsigned short, h);
}

// ---------------------------------------------------------------- kernel 1
// Wt[mat][h][c] = bf16(W[mat][c][h]), via LDS tile (coalesced both sides).
__global__ __launch_bounds__(256) void wtrans_kernel(
        const float* __restrict__ Wk,
        const float* __restrict__ Wq,
        const float* __restrict__ Wv,
        unsigned short* __restrict__ Wt) {
    __shared__ __align__(16) unsigned short tile[64][72];
    const float* Wm = (blockIdx.y == 0) ? Wk : ((blockIdx.y == 1) ? Wq : Wv);
    unsigned short* Wtm = Wt + blockIdx.y * (HH * CC);
    const int c0 = blockIdx.x * 64;
#pragma unroll
    for (int i = 0; i < 16; ++i) {
        int id = threadIdx.x + i * 256;         // 0..4095
        int c = id >> 6, h = id & 63;
        tile[c][h] = f2bf(Wm[(c0 + c) * HH + h]);   // coalesced read
    }
    __syncthreads();
#pragma unroll
    for (int i = 0; i < 16; ++i) {
        int id = threadIdx.x + i * 256;
        int h = id >> 6, c = id & 63;
        Wtm[h * CC + c0 + c] = tile[c][h];      // coalesced write
    }
}

// ---------------------------------------------------------------- kernel 2
// QKV projection: [32768,384]x[384,64] x3 with 16x16x32 bf16 MFMA.
// 512 thr = 2 wave-groups x 4 waves; group g accumulates c in [192g,192g+192),
// partials combined in LDS. k and vt written in MFMA fragment layouts.
__global__ __launch_bounds__(512) void qkv_kernel(
        const float* __restrict__ x,
        const unsigned short* __restrict__ Wt,     // [3][64][384] bf16
        unsigned short* __restrict__ q_ws,         // [32768][64] row-major, pre-scaled
        unsigned short* __restrict__ k_ws,         // fragment layout
        unsigned short* __restrict__ vt_ws) {      // fragment layout
    __shared__ __align__(16) f32x4 xacc[256 * 13];              // 53248 B
    __shared__ __align__(16) unsigned short vtile[64][72];      //  9216 B

    const int lane = threadIdx.x & 63;
    const int wv8  = threadIdx.x >> 6;     // 0..7
    const int grp  = wv8 >> 2;             // wave-group 0/1
    const int wg   = wv8 & 3;              // wave within group
    const int g256 = threadIdx.x & 255;    // thread id within group
    const int l15  = lane & 15;
    const int quad = lane >> 4;
    const int rb   = blockIdx.x * 64;
    const int row  = rb + wg * 16 + l15;           // A-frag m index

    f32x4 acc[3][4];
    const f32x4 zero = {0.f, 0.f, 0.f, 0.f};
#pragma unroll
    for (int m = 0; m < 3; ++m)
#pragma unroll
        for (int nt = 0; nt < 4; ++nt) acc[m][nt] = zero;

    const float* xrow = x + (long)row * CC + grp * 192;
#pragma unroll
    for (int ch = 0; ch < 3; ++ch) {
#pragma unroll
        for (int kg = 0; kg < 2; ++kg) {
            const int coff = ch * 64 + kg * 32 + quad * 8;      // within group's 192
            float4 u0 = *reinterpret_cast<const float4*>(xrow + coff);
            float4 u1 = *reinterpret_cast<const float4*>(xrow + coff + 4);
            bf16x8 a;
            a[0] = (__bf16)u0.x; a[1] = (__bf16)u0.y;
            a[2] = (__bf16)u0.z; a[3] = (__bf16)u0.w;
            a[4] = (__bf16)u1.x; a[5] = (__bf16)u1.y;
            a[6] = (__bf16)u1.z; a[7] = (__bf16)u1.w;
            const int gcoff = grp * 192 + coff;
#pragma unroll
            for (int m = 0; m < 3; ++m) {
                const unsigned short* wtm = Wt + m * (HH * CC);
#pragma unroll
                for (int nt = 0; nt < 4; ++nt) {
                    bf16x8 bfr = *reinterpret_cast<const bf16x8*>(
                        wtm + (nt * 16 + l15) * CC + gcoff);
                    acc[m][nt] = __builtin_amdgcn_mfma_f32_16x16x32_bf16(
                        a, bfr, acc[m][nt], 0, 0, 0);
                }
            }
        }
    }

    // combine the two groups' partials through LDS
    const int cidx = g256 * 13;
    if (grp == 1) {
#pragma unroll
        for (int m = 0; m < 3; ++m)
#pragma unroll
            for (int nt = 0; nt < 4; ++nt)
                xacc[cidx + m * 4 + nt] = acc[m][nt];
    }
    __syncthreads();

    if (grp == 0) {
#pragma unroll
        for (int m = 0; m < 3; ++m)
#pragma unroll
            for (int nt = 0; nt < 4; ++nt)
                acc[m][nt] += xacc[cidx + m * 4 + nt];

        // Epilogue. C-layout: acc[m][nt][r] = out[local row quad*4+r][h = nt*16+l15]
        const int rt = (rb >> 4) + wg;             // global 16-row tile index
#pragma unroll
        for (int nt = 0; nt < 4; ++nt) {
            const int h  = nt * 16 + l15;
            const int c8 = h >> 3;
            const int jj = h & 7;
#pragma unroll
            for (int r = 0; r < 4; ++r) {
                const int gr = rb + wg * 16 + quad * 4 + r;
                const int ii = quad * 4 + r;       // row within 16-tile
                k_ws[((rt * 8 + c8) * 16 + ii) * 8 + jj] = f2bf(acc[0][nt][r]);
                q_ws[gr * HH + h] = f2bf(acc[1][nt][r] * QSCALE);
                vtile[h][ii + wg * 16] = f2bf(acc[2][nt][r]);
            }
        }
    }
    __syncthreads();
    // vt fragment store: chunk id = (dt*8+sc)*16+ii, perfectly coalesced.
    {
        int id = threadIdx.x;                      // 0..511
        int dt = id >> 7, sc = (id >> 4) & 7, ii = id & 15;
        unsigned short* dst = vt_ws + (long)(rb >> 6) * 4096
                              + (dt * 8 + sc) * 128 + ii * 8;
        *reinterpret_cast<uint4*>(dst) =
            *reinterpret_cast<const uint4*>(&vtile[dt * 16 + ii][sc * 8]);
    }
}

// ---------------------------------------------------------------- kernel 3
// Flash attention, barrier-free k-loop, 1024 thr = 4 wave-groups x 4 waves.
// Group g handles k-tiles t = 4j+g independently; 3-round LDS merge at end.
__global__ __launch_bounds__(1024, 8) void attn_kernel(
        const unsigned short* __restrict__ q_ws,
        const unsigned short* __restrict__ k_ws,   // fragment layout
        const unsigned short* __restrict__ vt_ws,  // fragment layout
        float* __restrict__ out) {
    // P: per-wave 16 rows x 64 s, stride 64, XOR-swizzled (s ^ (q&7)<<3).
    __shared__ __align__(16) unsigned short P_lds[16 * 16 * 64]; // 32768 B
    __shared__ __align__(16) float xchg[64 * 65];                // 16640 B
    __shared__ float mx1[64], lx1[64];

    const int lane = threadIdx.x & 63;
    const int wv16 = threadIdx.x >> 6;     // 0..15
    const int grp  = wv16 >> 2;            // wave-group 0..3
    const int wg   = wv16 & 3;             // wave within group
    const int l15  = lane & 15;
    const int quad = lane >> 4;

    const int bid = blockIdx.x;
    const int b   = bid & 7;               // aligns b with XCD (round-robin)
    const int qt  = (TT / 64 - 1) - (bid >> 3);    // longest blocks first
    const int qrow = qt * 64 + wg * 16 + l15;      // this lane's q column index

    // Q fragments (B-operand: n=q=l15, k=d=quad*8+j), pre-scaled in q_ws
    const unsigned short* qbase = q_ws + (b * TT + qrow) * HH;
    const bf16x8 qf0 = *reinterpret_cast<const bf16x8*>(qbase + quad * 8);
    const bf16x8 qf1 = *reinterpret_cast<const bf16x8*>(qbase + 32 + quad * 8);

    const f32x4 zero = {0.f, 0.f, 0.f, 0.f};
    f32x4 o[4];
#pragma unroll
    for (int dt = 0; dt < 4; ++dt) o[dt] = zero;
    float mprev = -1e30f, lsum = 0.f;

    const int pbase = wv16 * 1024 + l15 * 64;      // this lane's P row base
    const int pxor  = (l15 & 7) << 3;              // bank swizzle

    for (int t = grp; t <= qt; t += 4) {
        const int s0 = t * 64;
        const unsigned short* ktile = k_ws + ((long)((b * TT + s0) >> 4)) * 1024;
        const unsigned short* vtile = vt_ws + ((long)((b * TT + s0) >> 6)) * 4096;

        // K A-frags: lane reads rows s=st*16+l15, cols quad*8.. — coalesced 1KB/load
        bf16x8 ka0[4], ka1[4];
#pragma unroll
        for (int st = 0; st < 4; ++st) {
            ka0[st] = *reinterpret_cast<const bf16x8*>(
                ktile + ((st * 8 + quad) * 16 + l15) * 8);
            ka1[st] = *reinterpret_cast<const bf16x8*>(
                ktile + ((st * 8 + 4 + quad) * 16 + l15) * 8);
        }
        // V B-frags: lane reads d=dt*16+l15, s=quad*8.. / 32+quad*8..
        bf16x8 vb0[4], vb1[4];
#pragma unroll
        for (int dt = 0; dt < 4; ++dt) {
            vb0[dt] = *reinterpret_cast<const bf16x8*>(
                vtile + dt * 1024 + quad * 128 + l15 * 8);
            vb1[dt] = *reinterpret_cast<const bf16x8*>(
                vtile + dt * 1024 + (4 + quad) * 128 + l15 * 8);
        }

        // S^T = K * Q^T : M=s(64 -> 4 tiles), N=q(16), K=d(64 -> 2 frags)
        f32x4 sc[4];
#pragma unroll
        for (int st = 0; st < 4; ++st) {
            f32x4 z = zero;
            z = __builtin_amdgcn_mfma_f32_16x16x32_bf16(ka0[st], qf0, z, 0, 0, 0);
            z = __builtin_amdgcn_mfma_f32_16x16x32_bf16(ka1[st], qf1, z, 0, 0, 0);
            sc[st] = z;
        }

        // causal mask (diagonal tile only): row = s = st*16+quad*4+r, col = q
        if (t == qt) {
#pragma unroll
            for (int st = 0; st < 4; ++st)
#pragma unroll
                for (int r = 0; r < 4; ++r) {
                    int sg = s0 + st * 16 + quad * 4 + r;
                    if (sg > qrow) sc[st][r] = -1e30f;
                }
        }

        // online softmax (scores already in log2 domain)
        float mloc = -1e30f;
#pragma unroll
        for (int st = 0; st < 4; ++st)
#pragma unroll
            for (int r = 0; r < 4; ++r) mloc = fmaxf(mloc, sc[st][r]);
        mloc = fmaxf(mloc, __shfl_xor(mloc, 16));
        mloc = fmaxf(mloc, __shfl_xor(mloc, 32));
        const float mnew = fmaxf(mprev, mloc);
        // max update is rare in late tiles: skip rescale when no row changed
        const unsigned long long anych = __ballot(mnew > mprev);
        float alpha = 1.0f;
        if (anych) alpha = EXP2(mprev - mnew);

        float psum = 0.f;
#pragma unroll
        for (int st = 0; st < 4; ++st) {
            union { unsigned short us[4]; uint2 u2; } pk;
#pragma unroll
            for (int r = 0; r < 4; ++r) {
                float p = EXP2(sc[st][r] - mnew);
                psum += p;
                pk.us[r] = f2bf(p);
            }
            *reinterpret_cast<uint2*>(
                &P_lds[pbase + ((st * 16 + quad * 4) ^ pxor)]) = pk.u2;
        }
        psum += __shfl_xor(psum, 16);
        psum += __shfl_xor(psum, 32);
        lsum = lsum * alpha + psum;
        mprev = mnew;

        if (anych) {
            // rescale O accumulator: O rows are q = quad*4+r
            float ar[4];
#pragma unroll
            for (int r = 0; r < 4; ++r) ar[r] = __shfl(alpha, quad * 4 + r);
#pragma unroll
            for (int dt = 0; dt < 4; ++dt)
#pragma unroll
                for (int r = 0; r < 4; ++r) o[dt][r] *= ar[r];
        }

        LDS_ROUNDTRIP_FENCE();   // wave-local P write->read ordering

        bf16x8 pf0 = *reinterpret_cast<const bf16x8*>(
            &P_lds[pbase + ((quad * 8) ^ pxor)]);
        bf16x8 pf1 = *reinterpret_cast<const bf16x8*>(
            &P_lds[pbase + ((32 + quad * 8) ^ pxor)]);
#pragma unroll
        for (int dt = 0; dt < 4; ++dt) {
            o[dt] = __builtin_amdgcn_mfma_f32_16x16x32_bf16(pf0, vb0[dt], o[dt], 0, 0, 0);
            o[dt] = __builtin_amdgcn_mfma_f32_16x16x32_bf16(pf1, vb1[dt], o[dt], 0, 0, 0);
        }
    }

    // ---- 3-round sequential merge of groups 1..3 into group 0 ----
    for (int rr = 1; rr < 4; ++rr) {
        __syncthreads();
        if (grp == rr) {
            if (quad == 0) { mx1[wg * 16 + l15] = mprev; lx1[wg * 16 + l15] = lsum; }
#pragma unroll
            for (int dt = 0; dt < 4; ++dt)
#pragma unroll
                for (int r = 0; r < 4; ++r)
                    xchg[(wg * 16 + quad * 4 + r) * 65 + dt * 16 + l15] = o[dt][r];
        }
        __syncthreads();
        if (grp == 0) {
            // per-row merge weights (rows q = wg*16 + quad*4 + r)
#pragma unroll
            for (int r = 0; r < 4; ++r) {
                const int row = wg * 16 + quad * 4 + r;
                const float m0r = __shfl(mprev, quad * 4 + r);
                const float m1r = mx1[row];
                const float ms  = fmaxf(m0r, m1r);
                const float w0  = EXP2(m0r - ms);
                const float w1  = EXP2(m1r - ms);
#pragma unroll
                for (int dt = 0; dt < 4; ++dt)
                    o[dt][r] = o[dt][r] * w0 + xchg[row * 65 + dt * 16 + l15] * w1;
            }
            // update lane-held stats (lane's own row q = wg*16 + l15)
            const float m1l = mx1[wg * 16 + l15];
            const float msl = fmaxf(mprev, m1l);
            lsum = EXP2(mprev - msl) * lsum + EXP2(m1l - msl) * lx1[wg * 16 + l15];
            mprev = msl;
        }
    }

    if (grp == 0) {
        float rl[4];
#pragma unroll
        for (int r = 0; r < 4; ++r) rl[r] = 1.0f / __shfl(lsum, quad * 4 + r);
        const int orow = qt * 64 + wg * 16 + quad * 4;
#pragma unroll
        for (int dt = 0; dt < 4; ++dt)
#pragma unroll
            for (int r = 0; r < 4; ++r)
                out[(long)(b * TT + orow + r) * HH + dt * 16 + l15] = o[dt][r] * rl[r];
    }
}

// ---------------------------------------------------------------- launch
extern "C" void kernel_launch(void* const* d_in, const int* in_sizes, int n_in,
                              void* d_out, int out_size, void* d_ws, size_t ws_size,
                              hipStream_t stream) {
    const float* x  = (const float*)d_in[0];
    const float* Wk = (const float*)d_in[1];
    const float* Wq = (const float*)d_in[2];
    const float* Wv = (const float*)d_in[3];
    float* out = (float*)d_out;

    char* ws = (char*)d_ws;
    unsigned short* Wt    = (unsigned short*)(ws);                         // 147456 B
    unsigned short* q_ws  = (unsigned short*)(ws + 147456);                // 4 MiB
    unsigned short* k_ws  = (unsigned short*)(ws + 147456 + 4194304);      // 4 MiB
    unsigned short* vt_ws = (unsigned short*)(ws + 147456 + 2 * 4194304);  // 4 MiB

    wtrans_kernel<<<dim3(6, 3), 256, 0, stream>>>(Wk, Wq, Wv, Wt);
    qkv_kernel<<<NROW / 64, 512, 0, stream>>>(x, Wt, q_ws, k_ws, vt_ws);
    attn_kernel<<<(TT / 64) * BB, 1024, 0, stream>>>(q_ws, k_ws, vt_ws, out);
}

// Round 9
// 167.457 us; speedup vs baseline: 3.1878x; 3.1878x over previous
//
#include <hip/hip_runtime.h>
#include <hip/hip_bf16.h>

// B=8, T=4096, C=384, H=64 causal single-head attention. fp32 in/out.
//
// Round-9: round 8's 4-way split-K was correct but (1024,8) forced VGPR
// cap 512/8=64 -> allocator squeezed to 32 -> 1.5 GB scratch spill
// (WRITE_SIZE 910 MB). One-line fix: (1024,4) = cap 128, the same cap
// round 7's identical body compiled to 64 VGPRs under. 16 waves = 4
// groups x 4 waves, group g takes tiles t = 4j+g: longest chain 32->16
// iterations; VGPR<=64 gives 2 blocks/CU = 32 waves/CU. Barrier-free
// k-loop (fragment-layout K/V direct from global). 3-round LDS merge.
//
//  k_frag layout: [rt=row/16][c8=col/8][i=row%16][j=col%8]   (bf16)
//  vt_frag layout: [st=row/64][dt=d/16][sc=s%64/8][i=d%16][j=s%8]

typedef __bf16 bf16x8 __attribute__((ext_vector_type(8)));
typedef float  f32x4  __attribute__((ext_vector_type(4)));

#define BB   8
#define TT   4096
#define CC   384
#define HH   64
#define NROW (BB*TT)       // 32768
// C^-0.5 * log2(e): fold softmax scale + exp2 conversion into q at projection
#define QSCALE (0.05103103630798288f * 1.4426950408889634f)

#if __has_builtin(__builtin_amdgcn_exp2f)
#define EXP2(x) __builtin_amdgcn_exp2f(x)
#else
#define EXP2(x) exp2f(x)
#endif

// Compiler memory fence + HW LDS drain: orders wave-local LDS write->read.
#define LDS_ROUNDTRIP_FENCE() __asm volatile("s_waitcnt lgkmcnt(0)" ::: "memory")

__device__ __forceinline__ unsigned short f2bf(float f) {
    __bf16 h = (__bf16)f;
    return __builtin_bit_cast(unsigned short, h);
}

// ---------------------------------------------------------------- kernel 1
// Wt[mat][h][c] = bf16(W[mat][c][h]), via LDS tile (coalesced both sides).
__global__ __launch_bounds__(256) void wtrans_kernel(
        const float* __restrict__ Wk,
        const float* __restrict__ Wq,
        const float* __restrict__ Wv,
        unsigned short* __restrict__ Wt) {
    __shared__ __align__(16) unsigned short tile[64][72];
    const float* Wm = (blockIdx.y == 0) ? Wk : ((blockIdx.y == 1) ? Wq : Wv);
    unsigned short* Wtm = Wt + blockIdx.y * (HH * CC);
    const int c0 = blockIdx.x * 64;
#pragma unroll
    for (int i = 0; i < 16; ++i) {
        int id = threadIdx.x + i * 256;         // 0..4095
        int c = id >> 6, h = id & 63;
        tile[c][h] = f2bf(Wm[(c0 + c) * HH + h]);   // coalesced read
    }
    __syncthreads();
#pragma unroll
    for (int i = 0; i < 16; ++i) {
        int id = threadIdx.x + i * 256;
        int h = id >> 6, c = id & 63;
        Wtm[h * CC + c0 + c] = tile[c][h];      // coalesced write
    }
}

// ---------------------------------------------------------------- kernel 2
// QKV projection: [32768,384]x[384,64] x3 with 16x16x32 bf16 MFMA.
// 512 thr = 2 wave-groups x 4 waves; group g accumulates c in [192g,192g+192),
// partials combined in LDS. k and vt written in MFMA fragment layouts.
__global__ __launch_bounds__(512) void qkv_kernel(
        const float* __restrict__ x,
        const unsigned short* __restrict__ Wt,     // [3][64][384] bf16
        unsigned short* __restrict__ q_ws,         // [32768][64] row-major, pre-scaled
        unsigned short* __restrict__ k_ws,         // fragment layout
        unsigned short* __restrict__ vt_ws) {      // fragment layout
    __shared__ __align__(16) f32x4 xacc[256 * 13];              // 53248 B
    __shared__ __align__(16) unsigned short vtile[64][72];      //  9216 B

    const int lane = threadIdx.x & 63;
    const int wv8  = threadIdx.x >> 6;     // 0..7
    const int grp  = wv8 >> 2;             // wave-group 0/1
    const int wg   = wv8 & 3;              // wave within group
    const int g256 = threadIdx.x & 255;    // thread id within group
    const int l15  = lane & 15;
    const int quad = lane >> 4;
    const int rb   = blockIdx.x * 64;
    const int row  = rb + wg * 16 + l15;           // A-frag m index

    f32x4 acc[3][4];
    const f32x4 zero = {0.f, 0.f, 0.f, 0.f};
#pragma unroll
    for (int m = 0; m < 3; ++m)
#pragma unroll
        for (int nt = 0; nt < 4; ++nt) acc[m][nt] = zero;

    const float* xrow = x + (long)row * CC + grp * 192;
#pragma unroll
    for (int ch = 0; ch < 3; ++ch) {
#pragma unroll
        for (int kg = 0; kg < 2; ++kg) {
            const int coff = ch * 64 + kg * 32 + quad * 8;      // within group's 192
            float4 u0 = *reinterpret_cast<const float4*>(xrow + coff);
            float4 u1 = *reinterpret_cast<const float4*>(xrow + coff + 4);
            bf16x8 a;
            a[0] = (__bf16)u0.x; a[1] = (__bf16)u0.y;
            a[2] = (__bf16)u0.z; a[3] = (__bf16)u0.w;
            a[4] = (__bf16)u1.x; a[5] = (__bf16)u1.y;
            a[6] = (__bf16)u1.z; a[7] = (__bf16)u1.w;
            const int gcoff = grp * 192 + coff;
#pragma unroll
            for (int m = 0; m < 3; ++m) {
                const unsigned short* wtm = Wt + m * (HH * CC);
#pragma unroll
                for (int nt = 0; nt < 4; ++nt) {
                    bf16x8 bfr = *reinterpret_cast<const bf16x8*>(
                        wtm + (nt * 16 + l15) * CC + gcoff);
                    acc[m][nt] = __builtin_amdgcn_mfma_f32_16x16x32_bf16(
                        a, bfr, acc[m][nt], 0, 0, 0);
                }
            }
        }
    }

    // combine the two groups' partials through LDS
    const int cidx = g256 * 13;
    if (grp == 1) {
#pragma unroll
        for (int m = 0; m < 3; ++m)
#pragma unroll
            for (int nt = 0; nt < 4; ++nt)
                xacc[cidx + m * 4 + nt] = acc[m][nt];
    }
    __syncthreads();

    if (grp == 0) {
#pragma unroll
        for (int m = 0; m < 3; ++m)
#pragma unroll
            for (int nt = 0; nt < 4; ++nt)
                acc[m][nt] += xacc[cidx + m * 4 + nt];

        // Epilogue. C-layout: acc[m][nt][r] = out[local row quad*4+r][h = nt*16+l15]
        const int rt = (rb >> 4) + wg;             // global 16-row tile index
#pragma unroll
        for (int nt = 0; nt < 4; ++nt) {
            const int h  = nt * 16 + l15;
            const int c8 = h >> 3;
            const int jj = h & 7;
#pragma unroll
            for (int r = 0; r < 4; ++r) {
                const int gr = rb + wg * 16 + quad * 4 + r;
                const int ii = quad * 4 + r;       // row within 16-tile
                k_ws[((rt * 8 + c8) * 16 + ii) * 8 + jj] = f2bf(acc[0][nt][r]);
                q_ws[gr * HH + h] = f2bf(acc[1][nt][r] * QSCALE);
                vtile[h][ii + wg * 16] = f2bf(acc[2][nt][r]);
            }
        }
    }
    __syncthreads();
    // vt fragment store: chunk id = (dt*8+sc)*16+ii, perfectly coalesced.
    {
        int id = threadIdx.x;                      // 0..511
        int dt = id >> 7, sc = (id >> 4) & 7, ii = id & 15;
        unsigned short* dst = vt_ws + (long)(rb >> 6) * 4096
                              + (dt * 8 + sc) * 128 + ii * 8;
        *reinterpret_cast<uint4*>(dst) =
            *reinterpret_cast<const uint4*>(&vtile[dt * 16 + ii][sc * 8]);
    }
}

// ---------------------------------------------------------------- kernel 3
// Flash attention, barrier-free k-loop, 1024 thr = 4 wave-groups x 4 waves.
// Group g handles k-tiles t = 4j+g independently; 3-round LDS merge at end.
// launch_bounds (1024,4): VGPR cap 128 (body fits in 64 — round 7) — do NOT
// raise the min-waves arg, it squeezes the allocator into spilling (round 8).
__global__ __launch_bounds__(1024, 4) void attn_kernel(
        const unsigned short* __restrict__ q_ws,
        const unsigned short* __restrict__ k_ws,   // fragment layout
        const unsigned short* __restrict__ vt_ws,  // fragment layout
        float* __restrict__ out) {
    // P: per-wave 16 rows x 64 s, stride 64, XOR-swizzled (s ^ (q&7)<<3).
    __shared__ __align__(16) unsigned short P_lds[16 * 16 * 64]; // 32768 B
    __shared__ __align__(16) float xchg[64 * 65];                // 16640 B
    __shared__ float mx1[64], lx1[64];

    const int lane = threadIdx.x & 63;
    const int wv16 = threadIdx.x >> 6;     // 0..15
    const int grp  = wv16 >> 2;            // wave-group 0..3
    const int wg   = wv16 & 3;             // wave within group
    const int l15  = lane & 15;
    const int quad = lane >> 4;

    const int bid = blockIdx.x;
    const int b   = bid & 7;               // aligns b with XCD (round-robin)
    const int qt  = (TT / 64 - 1) - (bid >> 3);    // longest blocks first
    const int qrow = qt * 64 + wg * 16 + l15;      // this lane's q column index

    // Q fragments (B-operand: n=q=l15, k=d=quad*8+j), pre-scaled in q_ws
    const unsigned short* qbase = q_ws + (b * TT + qrow) * HH;
    const bf16x8 qf0 = *reinterpret_cast<const bf16x8*>(qbase + quad * 8);
    const bf16x8 qf1 = *reinterpret_cast<const bf16x8*>(qbase + 32 + quad * 8);

    const f32x4 zero = {0.f, 0.f, 0.f, 0.f};
    f32x4 o[4];
#pragma unroll
    for (int dt = 0; dt < 4; ++dt) o[dt] = zero;
    float mprev = -1e30f, lsum = 0.f;

    const int pbase = wv16 * 1024 + l15 * 64;      // this lane's P row base
    const int pxor  = (l15 & 7) << 3;              // bank swizzle

    for (int t = grp; t <= qt; t += 4) {
        const int s0 = t * 64;
        const unsigned short* ktile = k_ws + ((long)((b * TT + s0) >> 4)) * 1024;
        const unsigned short* vtile = vt_ws + ((long)((b * TT + s0) >> 6)) * 4096;

        // K A-frags: lane reads rows s=st*16+l15, cols quad*8.. — coalesced 1KB/load
        bf16x8 ka0[4], ka1[4];
#pragma unroll
        for (int st = 0; st < 4; ++st) {
            ka0[st] = *reinterpret_cast<const bf16x8*>(
                ktile + ((st * 8 + quad) * 16 + l15) * 8);
            ka1[st] = *reinterpret_cast<const bf16x8*>(
                ktile + ((st * 8 + 4 + quad) * 16 + l15) * 8);
        }
        // V B-frags: lane reads d=dt*16+l15, s=quad*8.. / 32+quad*8..
        bf16x8 vb0[4], vb1[4];
#pragma unroll
        for (int dt = 0; dt < 4; ++dt) {
            vb0[dt] = *reinterpret_cast<const bf16x8*>(
                vtile + dt * 1024 + quad * 128 + l15 * 8);
            vb1[dt] = *reinterpret_cast<const bf16x8*>(
                vtile + dt * 1024 + (4 + quad) * 128 + l15 * 8);
        }

        // S^T = K * Q^T : M=s(64 -> 4 tiles), N=q(16), K=d(64 -> 2 frags)
        f32x4 sc[4];
#pragma unroll
        for (int st = 0; st < 4; ++st) {
            f32x4 z = zero;
            z = __builtin_amdgcn_mfma_f32_16x16x32_bf16(ka0[st], qf0, z, 0, 0, 0);
            z = __builtin_amdgcn_mfma_f32_16x16x32_bf16(ka1[st], qf1, z, 0, 0, 0);
            sc[st] = z;
        }

        // causal mask (diagonal tile only): row = s = st*16+quad*4+r, col = q
        if (t == qt) {
#pragma unroll
            for (int st = 0; st < 4; ++st)
#pragma unroll
                for (int r = 0; r < 4; ++r) {
                    int sg = s0 + st * 16 + quad * 4 + r;
                    if (sg > qrow) sc[st][r] = -1e30f;
                }
        }

        // online softmax (scores already in log2 domain)
        float mloc = -1e30f;
#pragma unroll
        for (int st = 0; st < 4; ++st)
#pragma unroll
            for (int r = 0; r < 4; ++r) mloc = fmaxf(mloc, sc[st][r]);
        mloc = fmaxf(mloc, __shfl_xor(mloc, 16));
        mloc = fmaxf(mloc, __shfl_xor(mloc, 32));
        const float mnew = fmaxf(mprev, mloc);
        // max update is rare in late tiles: skip rescale when no row changed
        const unsigned long long anych = __ballot(mnew > mprev);
        float alpha = 1.0f;
        if (anych) alpha = EXP2(mprev - mnew);

        float psum = 0.f;
#pragma unroll
        for (int st = 0; st < 4; ++st) {
            union { unsigned short us[4]; uint2 u2; } pk;
#pragma unroll
            for (int r = 0; r < 4; ++r) {
                float p = EXP2(sc[st][r] - mnew);
                psum += p;
                pk.us[r] = f2bf(p);
            }
            *reinterpret_cast<uint2*>(
                &P_lds[pbase + ((st * 16 + quad * 4) ^ pxor)]) = pk.u2;
        }
        psum += __shfl_xor(psum, 16);
        psum += __shfl_xor(psum, 32);
        lsum = lsum * alpha + psum;
        mprev = mnew;

        if (anych) {
            // rescale O accumulator: O rows are q = quad*4+r
            float ar[4];
#pragma unroll
            for (int r = 0; r < 4; ++r) ar[r] = __shfl(alpha, quad * 4 + r);
#pragma unroll
            for (int dt = 0; dt < 4; ++dt)
#pragma unroll
                for (int r = 0; r < 4; ++r) o[dt][r] *= ar[r];
        }

        LDS_ROUNDTRIP_FENCE();   // wave-local P write->read ordering

        bf16x8 pf0 = *reinterpret_cast<const bf16x8*>(
            &P_lds[pbase + ((quad * 8) ^ pxor)]);
        bf16x8 pf1 = *reinterpret_cast<const bf16x8*>(
            &P_lds[pbase + ((32 + quad * 8) ^ pxor)]);
#pragma unroll
        for (int dt = 0; dt < 4; ++dt) {
            o[dt] = __builtin_amdgcn_mfma_f32_16x16x32_bf16(pf0, vb0[dt], o[dt], 0, 0, 0);
            o[dt] = __builtin_amdgcn_mfma_f32_16x16x32_bf16(pf1, vb1[dt], o[dt], 0, 0, 0);
        }
    }

    // ---- 3-round sequential merge of groups 1..3 into group 0 ----
    for (int rr = 1; rr < 4; ++rr) {
        __syncthreads();
        if (grp == rr) {
            if (quad == 0) { mx1[wg * 16 + l15] = mprev; lx1[wg * 16 + l15] = lsum; }
#pragma unroll
            for (int dt = 0; dt < 4; ++dt)
#pragma unroll
                for (int r = 0; r < 4; ++r)
                    xchg[(wg * 16 + quad * 4 + r) * 65 + dt * 16 + l15] = o[dt][r];
        }
        __syncthreads();
        if (grp == 0) {
            // per-row merge weights (rows q = wg*16 + quad*4 + r)
#pragma unroll
            for (int r = 0; r < 4; ++r) {
                const int row = wg * 16 + quad * 4 + r;
                const float m0r = __shfl(mprev, quad * 4 + r);
                const float m1r = mx1[row];
                const float ms  = fmaxf(m0r, m1r);
                const float w0  = EXP2(m0r - ms);
                const float w1  = EXP2(m1r - ms);
#pragma unroll
                for (int dt = 0; dt < 4; ++dt)
                    o[dt][r] = o[dt][r] * w0 + xchg[row * 65 + dt * 16 + l15] * w1;
            }
            // update lane-held stats (lane's own row q = wg*16 + l15)
            const float m1l = mx1[wg * 16 + l15];
            const float msl = fmaxf(mprev, m1l);
            lsum = EXP2(mprev - msl) * lsum + EXP2(m1l - msl) * lx1[wg * 16 + l15];
            mprev = msl;
        }
    }

    if (grp == 0) {
        float rl[4];
#pragma unroll
        for (int r = 0; r < 4; ++r) rl[r] = 1.0f / __shfl(lsum, quad * 4 + r);
        const int orow = qt * 64 + wg * 16 + quad * 4;
#pragma unroll
        for (int dt = 0; dt < 4; ++dt)
#pragma unroll
            for (int r = 0; r < 4; ++r)
                out[(long)(b * TT + orow + r) * HH + dt * 16 + l15] = o[dt][r] * rl[r];
    }
}

// ---------------------------------------------------------------- launch
extern "C" void kernel_launch(void* const* d_in, const int* in_sizes, int n_in,
                              void* d_out, int out_size, void* d_ws, size_t ws_size,
                              hipStream_t stream) {
    const float* x  = (const float*)d_in[0];
    const float* Wk = (const float*)d_in[1];
    const float* Wq = (const float*)d_in[2];
    const float* Wv = (const float*)d_in[3];
    float* out = (float*)d_out;

    char* ws = (char*)d_ws;
    unsigned short* Wt    = (unsigned short*)(ws);                         // 147456 B
    unsigned short* q_ws  = (unsigned short*)(ws + 147456);                // 4 MiB
    unsigned short* k_ws  = (unsigned short*)(ws + 147456 + 4194304);      // 4 MiB
    unsigned short* vt_ws = (unsigned short*)(ws + 147456 + 2 * 4194304);  // 4 MiB

    wtrans_kernel<<<dim3(6, 3), 256, 0, stream>>>(Wk, Wq, Wv, Wt);
    qkv_kernel<<<NROW / 64, 512, 0, stream>>>(x, Wt, q_ws, k_ws, vt_ws);
    attn_kernel<<<(TT / 64) * BB, 1024, 0, stream>>>(q_ws, k_ws, vt_ws, out);
}